// Round 13
// baseline (3034.099 us; speedup 1.0000x reference)
//
#include <hip/hip_runtime.h>
#include <cstdint>
#include <cstddef>

#define BB    512
#define WINN  512
#define DIN   128
#define HIDN  256
#define DOUTN 64
#define PLENN 64
#define G4    1024   // 4*HID
#define SCALE2LOG2E 2.88539008177793f   // 2*log2(e)
#define XS    0.0416666666667f          // x int8 scale = 1/24

typedef short bf16x8 __attribute__((ext_vector_type(8)));
typedef float f32x4 __attribute__((ext_vector_type(4)));

__device__ __forceinline__ float tanh_fast(float xx) {
  float e = __expf(2.0f * xx);
  return 1.0f - 2.0f * __builtin_amdgcn_rcpf(e + 1.0f);
}
__device__ __forceinline__ float sigmoid_fast(float xx) {
  return __builtin_amdgcn_rcpf(1.0f + __expf(-xx));
}
__device__ __forceinline__ ushort f2bf(float f) {
  uint32_t u = __float_as_uint(f);
  return (ushort)((u + 0x7fffu + ((u >> 16) & 1u)) >> 16);
}
__device__ __forceinline__ float bflo(uint32_t u) { return __uint_as_float(u << 16); }
__device__ __forceinline__ float bfhi(uint32_t u) { return __uint_as_float(u & 0xffff0000u); }
__device__ __forceinline__ float ub(uint32_t raw, int byte) {
  return (float)((raw >> (byte * 8)) & 255u);       // -> v_cvt_f32_ubyteN
}
__device__ __forceinline__ uint32_t q8(float v, float sc) {
  float qf = fminf(fmaxf(fmaf(v, sc, 128.5f), 0.f), 255.f);
  return (uint32_t)(int)qf;
}
__device__ __forceinline__ float sterm(uint32_t raw, int byte, float tq, float mv, float acc) {
  float qf = ub(raw, byte);
  return fmaf(mv, __builtin_amdgcn_rcpf(
                    __builtin_amdgcn_exp2f(fmaf(qf, 0.0625f, tq)) + 1.f), acc);
}

// ---------------- one-time weight prep ----------------
// A32 layout: [512 k][192 r]; rows 0..127 = 2log2e*W[v][k], rows 128..191 = Wd[d][k<256] else 0
__global__ void prep_weights(const float* __restrict__ W, const float* __restrict__ W_ih,
                             const float* __restrict__ W_hh, const float* __restrict__ b_ih,
                             const float* __restrict__ b_hh, const float* __restrict__ Wd,
                             const float* __restrict__ V, const float* __restrict__ U,
                             float* __restrict__ A32, ushort* __restrict__ WihT16,
                             float* __restrict__ Wdt, float* __restrict__ bias,
                             float* __restrict__ m2vv,
                             ushort* __restrict__ Uh16, ushort* __restrict__ Ul16)
{
  int i = blockIdx.x * 256 + threadIdx.x;
  if (i < 512 * 192) {
    int k = i / 192, r = i - k * 192;
    float val;
    if (r < 128) val = SCALE2LOG2E * W[r * 512 + k];
    else         val = (k < 256) ? Wd[(r - 128) * 256 + k] : 0.f;
    A32[i] = val;
  }
  if (i < 448 * 1024) {
    int k = i >> 10, g = i & 1023;
    float v = (k < 192) ? W_ih[g * 192 + k] : W_hh[g * 256 + (k - 192)];
    WihT16[i] = f2bf(v);
  }
  if (i < 256 * 64) { int h = i >> 6, d = i & 63; Wdt[i] = Wd[d * 256 + h]; }
  if (i < 1024) bias[i] = b_ih[i] + b_hh[i];
  if (i < 128) m2vv[i] = -2.0f * V[i];
  if (i < 128 * 128) {
    float us = SCALE2LOG2E * U[i];
    ushort h = f2bf(us);
    float lo = us - __uint_as_float((uint32_t)h << 16);
    Uh16[i] = h;
    Ul16[i] = f2bf(lo);
  }
}

// ---------------- one-time x -> bf16 copy + biased-uint8 copy ----------------
__global__ __launch_bounds__(256) void convert_x(const float* __restrict__ x,
                                                 ushort* __restrict__ x16,
                                                 unsigned char* __restrict__ x8q)
{
  size_t i = ((size_t)blockIdx.x * 256 + threadIdx.x) * 8;
  float4 a = *(const float4*)(x + i);
  float4 b = *(const float4*)(x + i + 4);
  uint4 o;
  o.x = (uint32_t)f2bf(a.x) | ((uint32_t)f2bf(a.y) << 16);
  o.y = (uint32_t)f2bf(a.z) | ((uint32_t)f2bf(a.w) << 16);
  o.z = (uint32_t)f2bf(b.x) | ((uint32_t)f2bf(b.y) << 16);
  o.w = (uint32_t)f2bf(b.z) | ((uint32_t)f2bf(b.w) << 16);
  *(uint4*)(x16 + i) = o;
  uint2 p;
  p.x = q8(a.x, 24.f) | (q8(a.y, 24.f) << 8) | (q8(a.z, 24.f) << 16) | (q8(a.w, 24.f) << 24);
  p.y = q8(b.x, 24.f) | (q8(b.y, 24.f) << 8) | (q8(b.z, 24.f) << 16) | (q8(b.w, 24.f) << 24);
  *(uint2*)(x8q + i) = p;
}

// ---------------- one-time UkT8[b][w][v] = u8( 16*(2log2e*U@x^T) + 128 ), MFMA ----------------
// B-vectors double-buffered across wt: loads of tile wt+1 overlap MFMAs of tile wt.
__global__ __launch_bounds__(256) void compute_uk_mfma(const ushort* __restrict__ x16,
                                                       const ushort* __restrict__ Uh16,
                                                       const ushort* __restrict__ Ul16,
                                                       unsigned char* __restrict__ UkT8)
{
  int bidx = blockIdx.x;
  int b   = bidx >> 3;
  int sub = bidx & 7;
  int vs  = sub >> 2;
  int wsb = sub & 3;
  int tid = threadIdx.x;
  int wave = tid >> 6;
  int lane = tid & 63;
  int lr = lane & 15;
  int lk = lane >> 4;

  int v_base = vs * 64 + wave * 16;
  int w_blk  = wsb * 128;

  bf16x8 ah[4], al[4];
#pragma unroll
  for (int kt = 0; kt < 4; ++kt) {
    ah[kt] = *(const bf16x8*)(Uh16 + (size_t)(v_base + lr) * 128 + kt * 32 + lk * 8);
    al[kt] = *(const bf16x8*)(Ul16 + (size_t)(v_base + lr) * 128 + kt * 32 + lk * 8);
  }

  const ushort* bbase = x16 + ((size_t)b * 512 + w_blk + lr) * 128 + lk * 8;
  bf16x8 bv[2][4];
#pragma unroll
  for (int kt = 0; kt < 4; ++kt)
    bv[0][kt] = *(const bf16x8*)(bbase + kt * 32);

#pragma unroll
  for (int wt = 0; wt < 8; ++wt) {
    int cur = wt & 1;
    if (wt < 7) {
#pragma unroll
      for (int kt = 0; kt < 4; ++kt)
        bv[cur ^ 1][kt] = *(const bf16x8*)(bbase + (size_t)(wt + 1) * 16 * 128 + kt * 32);
    }
    f32x4 acch = {0.f, 0.f, 0.f, 0.f};
    f32x4 accl = {0.f, 0.f, 0.f, 0.f};
#pragma unroll
    for (int kt = 0; kt < 4; ++kt) {
      acch = __builtin_amdgcn_mfma_f32_16x16x32_bf16(ah[kt], bv[cur][kt], acch, 0, 0, 0);
      accl = __builtin_amdgcn_mfma_f32_16x16x32_bf16(al[kt], bv[cur][kt], accl, 0, 0, 0);
    }
    f32x4 acc = acch + accl;
    uint32_t q = q8(acc[0], 16.f) | (q8(acc[1], 16.f) << 8) |
                 (q8(acc[2], 16.f) << 16) | (q8(acc[3], 16.f) << 24);
    int w0 = w_blk + wt * 16;
    *(uint32_t*)(UkT8 + ((size_t)b * 512 + w0 + lr) * 128 + v_base + lk * 4) = q;
  }
}

// ---------------- per-step K1: lstm(t-1) + [tqs; y] = A32 @ [s;c] ----------------
__global__ __launch_bounds__(512) void lstm_qy(const float* __restrict__ g0,
    const float* __restrict__ g1, const float* __restrict__ c_in,
    float* __restrict__ c_out, float* __restrict__ s, float* __restrict__ ybuf,
    const float* __restrict__ A32, const float* __restrict__ bd,
    float* __restrict__ tqs_g, float* __restrict__ outy, int t)
{
  __shared__ float q_lds[8][512];
  int tid = threadIdx.x;
  int b0 = blockIdx.x * 8;
  int strip = blockIdx.y;

  if (t > 0) {
#pragma unroll
    for (int rep = 0; rep < 4; ++rep) {
      int cell = tid + rep * 512;
      int bl = cell >> 8, h = cell & 255;
      int b = b0 + bl;
      size_t gb = (size_t)b * 1024;
      float gi = g0[gb + h]       + g1[gb + h];
      float gf = g0[gb + 256 + h] + g1[gb + 256 + h];
      float gg = g0[gb + 512 + h] + g1[gb + 512 + h];
      float go = g0[gb + 768 + h] + g1[gb + 768 + h];
      float cv = c_in[b * 256 + h];
      float cn = sigmoid_fast(gf) * cv + sigmoid_fast(gi) * tanh_fast(gg);
      float sn = sigmoid_fast(go) * tanh_fast(cn);
      q_lds[bl][h] = sn;
      q_lds[bl][256 + h] = cn;
      if (strip == 0) { c_out[b * 256 + h] = cn; s[b * 256 + h] = sn; }
    }
  } else {
#pragma unroll
    for (int rep = 0; rep < 4; ++rep) {
      int cell = tid + rep * 512;
      int bl = cell >> 8, h = cell & 255;
      q_lds[bl][h] = 0.f; q_lds[bl][256 + h] = 0.f;
    }
  }
  __syncthreads();

  int r = strip * 64 + (tid & 63);
  int tb = tid >> 6;
  int b = b0 + tb;
  float acc0 = (r < 128) ? -8.0f : bd[r - 128];
  float acc1 = 0.f, acc2 = 0.f, acc3 = 0.f;
  const float* ap = A32 + r;
  const float* qp = &q_lds[tb][0];
#pragma unroll 8
  for (int k = 0; k < 512; k += 4) {
    float4 q4 = *(const float4*)(qp + k);           // ds_read_b128, wave-broadcast
    acc0 = fmaf(ap[(size_t)(k + 0) * 192], q4.x, acc0);
    acc1 = fmaf(ap[(size_t)(k + 1) * 192], q4.y, acc1);
    acc2 = fmaf(ap[(size_t)(k + 2) * 192], q4.z, acc2);
    acc3 = fmaf(ap[(size_t)(k + 3) * 192], q4.w, acc3);
  }
  float acc = (acc0 + acc1) + (acc2 + acc3);
  if (r < 128) {
    tqs_g[b * 128 + r] = acc;                         // = 2log2e*wq - 8
  } else if (t > 0) {
    int d = r - 128;
    ybuf[b * 64 + d] = acc;
    outy[(size_t)b * PLENN * 64 + (size_t)(t - 1) * 64 + d] = acc;
  }
}

// ---------------- per-step K2: e-pass + softmax + ctx (pipelined streams) ----------------
__global__ __launch_bounds__(512, 4) void attn_stream(const unsigned char* __restrict__ UkT8,
    const unsigned char* __restrict__ x8q, const float* __restrict__ tqs_g,
    const float* __restrict__ m2vv_g, float* __restrict__ ctx,
    float* __restrict__ wout, int t)
{
  __shared__ float tqs[128];
  __shared__ float m2vv[128];
  __shared__ float e_sh[512];
  __shared__ float watt[512];
  __shared__ float red[16];
  __shared__ float cp2[544];
  __shared__ float scratch[4096];
  int tid = threadIdx.x;
  int b = blockIdx.x;

  if (tid < 128) tqs[tid] = tqs_g[b * 128 + tid];
  else if (tid < 256) m2vv[tid - 128] = m2vv_g[tid - 128];
  __syncthreads();

  // ---- phase C: e-pass; 4-deep rotating prefetch of uint4 rows ----
  {
    int vs = tid & 7, wg = tid >> 3;
    const unsigned char* base = UkT8 + ((size_t)b * 512 + wg) * 128 + vs * 16;
    uint4 buf[4];
#pragma unroll
    for (int i = 0; i < 4; ++i)
      buf[i] = *(const uint4*)(base + (size_t)i * 64 * 128);
    float tq[16], mv[16];
#pragma unroll
    for (int q4 = 0; q4 < 4; ++q4) {
      float4 t4 = *(const float4*)&tqs[vs * 16 + q4 * 4];
      float4 m4 = *(const float4*)&m2vv[vs * 16 + q4 * 4];
      tq[q4 * 4 + 0] = t4.x; tq[q4 * 4 + 1] = t4.y; tq[q4 * 4 + 2] = t4.z; tq[q4 * 4 + 3] = t4.w;
      mv[q4 * 4 + 0] = m4.x; mv[q4 * 4 + 1] = m4.y; mv[q4 * 4 + 2] = m4.z; mv[q4 * 4 + 3] = m4.w;
    }
    float a8[8];
#pragma unroll
    for (int wi = 0; wi < 8; ++wi) {
      uint4 r0 = buf[wi & 3];
      if (wi < 4)
        buf[wi & 3] = *(const uint4*)(base + (size_t)(wi + 4) * 64 * 128);
      float a = 0.f;
      a = sterm(r0.x, 0, tq[ 0], mv[ 0], a);
      a = sterm(r0.x, 1, tq[ 1], mv[ 1], a);
      a = sterm(r0.x, 2, tq[ 2], mv[ 2], a);
      a = sterm(r0.x, 3, tq[ 3], mv[ 3], a);
      a = sterm(r0.y, 0, tq[ 4], mv[ 4], a);
      a = sterm(r0.y, 1, tq[ 5], mv[ 5], a);
      a = sterm(r0.y, 2, tq[ 6], mv[ 6], a);
      a = sterm(r0.y, 3, tq[ 7], mv[ 7], a);
      a = sterm(r0.z, 0, tq[ 8], mv[ 8], a);
      a = sterm(r0.z, 1, tq[ 9], mv[ 9], a);
      a = sterm(r0.z, 2, tq[10], mv[10], a);
      a = sterm(r0.z, 3, tq[11], mv[11], a);
      a = sterm(r0.w, 0, tq[12], mv[12], a);
      a = sterm(r0.w, 1, tq[13], mv[13], a);
      a = sterm(r0.w, 2, tq[14], mv[14], a);
      a = sterm(r0.w, 3, tq[15], mv[15], a);
      a8[wi] = a;
    }
#pragma unroll
    for (int wi = 0; wi < 8; ++wi) {
      a8[wi] += __shfl_xor(a8[wi], 1);
      a8[wi] += __shfl_xor(a8[wi], 2);
      a8[wi] += __shfl_xor(a8[wi], 4);
    }
    if (vs == 0) {
#pragma unroll
      for (int wi = 0; wi < 8; ++wi) e_sh[wg + wi * 64] = a8[wi];
    }
  }
  __syncthreads();

  // ---- softmax over 512 w ----
  float e = e_sh[tid];
  float m = e;
#pragma unroll
  for (int o = 32; o > 0; o >>= 1) m = fmaxf(m, __shfl_xor(m, o));
  if ((tid & 63) == 0) red[tid >> 6] = m;
  __syncthreads();
  float M = red[0];
#pragma unroll
  for (int i2 = 1; i2 < 8; ++i2) M = fmaxf(M, red[i2]);
  float p = __expf(e - M);
  float wsum = p;
#pragma unroll
  for (int o = 32; o > 0; o >>= 1) wsum += __shfl_xor(wsum, o);
  if ((tid & 63) == 0) red[8 + (tid >> 6)] = wsum;
  __syncthreads();
  float S = red[8] + red[9] + red[10] + red[11] + red[12] + red[13] + red[14] + red[15];
  float wv = p * __builtin_amdgcn_rcpf(S);
  watt[tid] = wv;
  wout[(size_t)b * PLENN * 512 + (size_t)t * 512 + tid] = wv;
  __syncthreads();

  // ---- phase E: ctx partials; 8-deep rotating prefetch of uint2 rows ----
  {
    int dg = tid & 15, wch = tid >> 4;
    const unsigned char* xp = x8q + ((size_t)(b * 512 + wch * 16)) * 128 + dg * 8;
    uint2 rbuf[8];
#pragma unroll
    for (int i = 0; i < 8; ++i)
      rbuf[i] = *(const uint2*)(xp + (size_t)i * 128);
    float a8[8];
#pragma unroll
    for (int i = 0; i < 8; ++i) a8[i] = 0.f;
#pragma unroll
    for (int wi = 0; wi < 16; ++wi) {
      uint2 raw = rbuf[wi & 7];
      if (wi < 8)
        rbuf[wi & 7] = *(const uint2*)(xp + (size_t)(wi + 8) * 128);
      float wgt = watt[wch * 16 + wi];
      a8[0] = fmaf(wgt, ub(raw.x, 0), a8[0]);
      a8[1] = fmaf(wgt, ub(raw.x, 1), a8[1]);
      a8[2] = fmaf(wgt, ub(raw.x, 2), a8[2]);
      a8[3] = fmaf(wgt, ub(raw.x, 3), a8[3]);
      a8[4] = fmaf(wgt, ub(raw.y, 0), a8[4]);
      a8[5] = fmaf(wgt, ub(raw.y, 1), a8[5]);
      a8[6] = fmaf(wgt, ub(raw.y, 2), a8[6]);
      a8[7] = fmaf(wgt, ub(raw.y, 3), a8[7]);
    }
    int rot = (dg + wch) & 7;
    int sbase = wch * 128 + dg * 8;
#pragma unroll
    for (int i = 0; i < 8; ++i) scratch[sbase + ((i + rot) & 7)] = a8[i];
  }
  __syncthreads();
  {
    int p2 = tid >> 7, d = tid & 127;
    float a = 0.f;
#pragma unroll
    for (int k = 0; k < 8; ++k) {
      int wch = p2 * 8 + k;
      a += scratch[wch * 128 + (d & ~7) + (((d & 7) + (d >> 3) + wch) & 7)];
    }
    cp2[p2 * 136 + d] = a;
  }
  __syncthreads();
  if (tid < 128) {
    float a = cp2[tid] + cp2[136 + tid] + cp2[272 + tid] + cp2[408 + tid];
    ctx[b * 128 + tid] = fmaf(a, XS, -128.0f * XS);   // sum(w)==1
  }
}

// ---------------- per-step K3: gates GEMM (bf16 B), 32x64 tiles ----------------
__global__ __launch_bounds__(256) void gates_gemm(const float* __restrict__ y,
    const float* __restrict__ ctx, const float* __restrict__ s,
    const ushort* __restrict__ WihT16, const float* __restrict__ bias,
    float* __restrict__ g0, float* __restrict__ g1)
{
  __shared__ float As[32][36];
  __shared__ float Bs[32][68];
  int tid = threadIdx.x;
  int bm = blockIdx.x;
  int bn = blockIdx.y;
  int kz = blockIdx.z;
  int tr = tid & 15, tc = tid >> 4;
  float acc[2][4];
#pragma unroll
  for (int i = 0; i < 2; ++i)
#pragma unroll
    for (int j = 0; j < 4; ++j) acc[i][j] = 0.f;

  for (int kt = 0; kt < 7; ++kt) {
    int k0 = kz * 224 + kt * 32;
    const float* Ab; int stride, off;
    if (k0 < 64)       { Ab = y;   stride = 64;  off = 0; }
    else if (k0 < 192) { Ab = ctx; stride = 128; off = 64; }
    else               { Ab = s;   stride = 256; off = 192; }
#pragma unroll
    for (int i = 0; i < 4; ++i) {
      int idx = tid + i * 256;
      int r = idx >> 5, kk = idx & 31;
      As[kk][r] = Ab[(size_t)(bm * 32 + r) * stride + (k0 - off) + kk];
    }
#pragma unroll
    for (int i = 0; i < 4; ++i) {
      int idx = tid + i * 256;
      int kk = idx >> 5, cp = idx & 31;
      uint32_t w2 = *(const uint32_t*)(WihT16 + (size_t)(k0 + kk) * 1024 + bn * 64 + cp * 2);
      Bs[kk][cp * 2]     = bflo(w2);
      Bs[kk][cp * 2 + 1] = bfhi(w2);
    }
    __syncthreads();
#pragma unroll 8
    for (int kk = 0; kk < 32; ++kk) {
      float2 a2 = *(const float2*)&As[kk][tr * 2];
      float4 b4 = *(const float4*)&Bs[kk][tc * 4];
      acc[0][0] = fmaf(a2.x, b4.x, acc[0][0]);
      acc[0][1] = fmaf(a2.x, b4.y, acc[0][1]);
      acc[0][2] = fmaf(a2.x, b4.z, acc[0][2]);
      acc[0][3] = fmaf(a2.x, b4.w, acc[0][3]);
      acc[1][0] = fmaf(a2.y, b4.x, acc[1][0]);
      acc[1][1] = fmaf(a2.y, b4.y, acc[1][1]);
      acc[1][2] = fmaf(a2.y, b4.z, acc[1][2]);
      acc[1][3] = fmaf(a2.y, b4.w, acc[1][3]);
    }
    __syncthreads();
  }
  float* dst = kz ? g1 : g0;
#pragma unroll
  for (int i = 0; i < 2; ++i) {
    int bb = bm * 32 + tr * 2 + i;
    int g  = bn * 64 + tc * 4;
    float4 o4;
    o4.x = acc[i][0] + (kz == 0 ? bias[g + 0] : 0.f);
    o4.y = acc[i][1] + (kz == 0 ? bias[g + 1] : 0.f);
    o4.z = acc[i][2] + (kz == 0 ? bias[g + 2] : 0.f);
    o4.w = acc[i][3] + (kz == 0 ? bias[g + 3] : 0.f);
    *(float4*)(dst + (size_t)bb * 1024 + g) = o4;
  }
}

// ---------------- tail: final lstm + y ----------------
__global__ __launch_bounds__(256) void lstm_tail(const float* __restrict__ g0,
    const float* __restrict__ g1, const float* __restrict__ c_in,
    const float* __restrict__ Wdt, const float* __restrict__ bd,
    float* __restrict__ outy, int t)
{
  __shared__ float ssh[256];
  int b = blockIdx.x, h = threadIdx.x;
  size_t gb = (size_t)b * 1024;
  float gi = g0[gb + h]       + g1[gb + h];
  float gf = g0[gb + 256 + h] + g1[gb + 256 + h];
  float gg = g0[gb + 512 + h] + g1[gb + 512 + h];
  float go = g0[gb + 768 + h] + g1[gb + 768 + h];
  float cv = c_in[b * 256 + h];
  float cn = sigmoid_fast(gf) * cv + sigmoid_fast(gi) * tanh_fast(gg);
  float sn = sigmoid_fast(go) * tanh_fast(cn);
  ssh[h] = sn;
  __syncthreads();
  if (h < 64) {
    float a = bd[h];
#pragma unroll 4
    for (int k = 0; k < 256; ++k) a = fmaf(ssh[k], Wdt[k * 64 + h], a);
    outy[(size_t)b * PLENN * 64 + (size_t)t * 64 + h] = a;
  }
}

extern "C" void kernel_launch(void* const* d_in, const int* in_sizes, int n_in,
                              void* d_out, int out_size, void* d_ws, size_t ws_size,
                              hipStream_t stream)
{
  (void)in_sizes; (void)n_in; (void)out_size; (void)ws_size;
  const float* x    = (const float*)d_in[0];
  const float* V    = (const float*)d_in[2];
  const float* W    = (const float*)d_in[3];
  const float* U    = (const float*)d_in[4];
  const float* W_ih = (const float*)d_in[5];
  const float* W_hh = (const float*)d_in[6];
  const float* b_ih = (const float*)d_in[7];
  const float* b_hh = (const float*)d_in[8];
  const float* Wd   = (const float*)d_in[9];
  const float* bd   = (const float*)d_in[10];

  float* out  = (float*)d_out;
  float* outy = out;                                   // predict_y (B,64,64)
  float* outw = out + (size_t)BB * PLENN * DOUTN;      // weight    (B,64,512)

  float* ws = (float*)d_ws;
  size_t o = 0;
  unsigned char* UkT8 = (unsigned char*)(ws + o); o += (size_t)BB * DIN * WINN / 4;
  unsigned char* x8q  = (unsigned char*)(ws + o); o += (size_t)BB * WINN * DIN / 4;
  ushort* x16  = (ushort*)(ws + o); o += (size_t)BB * WINN * DIN / 2;
  float* A32  = ws + o; o += 512 * 192;
  ushort* WihT16 = (ushort*)(ws + o); o += 448 * 1024 / 2;
  float* Wdt  = ws + o; o += 256 * 64;
  float* bias = ws + o; o += 1024;
  float* m2vv = ws + o; o += 128;
  ushort* Uh16 = (ushort*)(ws + o); o += 128 * 128 / 2;
  ushort* Ul16 = (ushort*)(ws + o); o += 128 * 128 / 2;
  float* sbuf = ws + o; o += (size_t)BB * HIDN;
  float* cbuf = ws + o; o += (size_t)2 * BB * HIDN;    // ping-pong
  float* ybuf = ws + o; o += (size_t)BB * DOUTN;
  float* ctx  = ws + o; o += (size_t)BB * DIN;
  float* tqs_g = ws + o; o += (size_t)BB * DIN;
  float* g0   = ws + o; o += (size_t)BB * G4;
  float* g1   = ws + o; o += (size_t)BB * G4;

  hipMemsetAsync(sbuf, 0, (size_t)BB * HIDN * sizeof(float), stream);
  hipMemsetAsync(cbuf, 0, (size_t)2 * BB * HIDN * sizeof(float), stream);
  hipMemsetAsync(ybuf, 0, (size_t)BB * DOUTN * sizeof(float), stream);

  prep_weights<<<1792, 256, 0, stream>>>(W, W_ih, W_hh, b_ih, b_hh, Wd, V, U,
                                         A32, WihT16, Wdt, bias, m2vv, Uh16, Ul16);
  convert_x<<<16384, 256, 0, stream>>>(x, x16, x8q);
  compute_uk_mfma<<<4096, 256, 0, stream>>>(x16, Uh16, Ul16, UkT8);

  for (int t = 0; t < PLENN; ++t) {
    const float* cin = cbuf + (size_t)((t + 1) & 1) * BB * HIDN;
    float* cout      = cbuf + (size_t)(t & 1) * BB * HIDN;
    lstm_qy<<<dim3(64, 3), 512, 0, stream>>>(g0, g1, cin, cout, sbuf, ybuf,
                                             A32, bd, tqs_g, outy, t);
    attn_stream<<<BB, 512, 0, stream>>>(UkT8, x8q, tqs_g, m2vv, ctx, outw, t);
    gates_gemm<<<dim3(16, 16, 2), 256, 0, stream>>>(ybuf, ctx, sbuf, WihT16, bias, g0, g1);
  }
  lstm_tail<<<BB, 256, 0, stream>>>(g0, g1, cbuf + (size_t)BB * HIDN,
                                    Wdt, bd, outy, PLENN - 1);
}

// Round 14
// 2956.068 us; speedup vs baseline: 1.0264x; 1.0264x over previous
//
#include <hip/hip_runtime.h>
#include <cstdint>
#include <cstddef>

#define BB    512
#define WINN  512
#define DIN   128
#define HIDN  256
#define DOUTN 64
#define PLENN 64
#define G4    1024   // 4*HID
#define SCALE2LOG2E 2.88539008177793f   // 2*log2(e)
#define XS    0.0416666666667f          // x int8 scale = 1/24

typedef short bf16x8 __attribute__((ext_vector_type(8)));
typedef float f32x4 __attribute__((ext_vector_type(4)));

__device__ __forceinline__ float tanh_fast(float xx) {
  float e = __expf(2.0f * xx);
  return 1.0f - 2.0f * __builtin_amdgcn_rcpf(e + 1.0f);
}
__device__ __forceinline__ float sigmoid_fast(float xx) {
  return __builtin_amdgcn_rcpf(1.0f + __expf(-xx));
}
__device__ __forceinline__ ushort f2bf(float f) {
  uint32_t u = __float_as_uint(f);
  return (ushort)((u + 0x7fffu + ((u >> 16) & 1u)) >> 16);
}
__device__ __forceinline__ float bflo(uint32_t u) { return __uint_as_float(u << 16); }
__device__ __forceinline__ float bfhi(uint32_t u) { return __uint_as_float(u & 0xffff0000u); }
__device__ __forceinline__ float ub(uint32_t raw, int byte) {
  return (float)((raw >> (byte * 8)) & 255u);       // -> v_cvt_f32_ubyteN
}
__device__ __forceinline__ uint32_t q8(float v, float sc) {
  float qf = fminf(fmaxf(fmaf(v, sc, 128.5f), 0.f), 255.f);
  return (uint32_t)(int)qf;
}
__device__ __forceinline__ float sterm(uint32_t raw, int byte, float tq, float mv, float acc) {
  float qf = ub(raw, byte);
  return fmaf(mv, __builtin_amdgcn_rcpf(
                    __builtin_amdgcn_exp2f(fmaf(qf, 0.0625f, tq)) + 1.f), acc);
}

// ---------------- one-time weight prep ----------------
// A32 layout: [512 k][192 r]; rows 0..127 = 2log2e*W[v][k], rows 128..191 = Wd[d][k<256] else 0
__global__ void prep_weights(const float* __restrict__ W, const float* __restrict__ W_ih,
                             const float* __restrict__ W_hh, const float* __restrict__ b_ih,
                             const float* __restrict__ b_hh, const float* __restrict__ Wd,
                             const float* __restrict__ V, const float* __restrict__ U,
                             float* __restrict__ A32, ushort* __restrict__ WihT16,
                             float* __restrict__ Wdt, float* __restrict__ bias,
                             float* __restrict__ m2vv,
                             ushort* __restrict__ Uh16, ushort* __restrict__ Ul16)
{
  int i = blockIdx.x * 256 + threadIdx.x;
  if (i < 512 * 192) {
    int k = i / 192, r = i - k * 192;
    float val;
    if (r < 128) val = SCALE2LOG2E * W[r * 512 + k];
    else         val = (k < 256) ? Wd[(r - 128) * 256 + k] : 0.f;
    A32[i] = val;
  }
  if (i < 448 * 1024) {
    int k = i >> 10, g = i & 1023;
    float v = (k < 192) ? W_ih[g * 192 + k] : W_hh[g * 256 + (k - 192)];
    WihT16[i] = f2bf(v);
  }
  if (i < 256 * 64) { int h = i >> 6, d = i & 63; Wdt[i] = Wd[d * 256 + h]; }
  if (i < 1024) bias[i] = b_ih[i] + b_hh[i];
  if (i < 128) m2vv[i] = -2.0f * V[i];
  if (i < 128 * 128) {
    float us = SCALE2LOG2E * U[i];
    ushort h = f2bf(us);
    float lo = us - __uint_as_float((uint32_t)h << 16);
    Uh16[i] = h;
    Ul16[i] = f2bf(lo);
  }
}

// ---------------- one-time x -> bf16 copy + biased-uint8 copy ----------------
__global__ __launch_bounds__(256) void convert_x(const float* __restrict__ x,
                                                 ushort* __restrict__ x16,
                                                 unsigned char* __restrict__ x8q)
{
  size_t i = ((size_t)blockIdx.x * 256 + threadIdx.x) * 8;
  float4 a = *(const float4*)(x + i);
  float4 b = *(const float4*)(x + i + 4);
  uint4 o;
  o.x = (uint32_t)f2bf(a.x) | ((uint32_t)f2bf(a.y) << 16);
  o.y = (uint32_t)f2bf(a.z) | ((uint32_t)f2bf(a.w) << 16);
  o.z = (uint32_t)f2bf(b.x) | ((uint32_t)f2bf(b.y) << 16);
  o.w = (uint32_t)f2bf(b.z) | ((uint32_t)f2bf(b.w) << 16);
  *(uint4*)(x16 + i) = o;
  uint2 p;
  p.x = q8(a.x, 24.f) | (q8(a.y, 24.f) << 8) | (q8(a.z, 24.f) << 16) | (q8(a.w, 24.f) << 24);
  p.y = q8(b.x, 24.f) | (q8(b.y, 24.f) << 8) | (q8(b.z, 24.f) << 16) | (q8(b.w, 24.f) << 24);
  *(uint2*)(x8q + i) = p;
}

// ---------------- one-time UkT8[b][w][v] = u8( 16*(2log2e*U@x^T) + 128 ), MFMA ----------------
__global__ __launch_bounds__(256) void compute_uk_mfma(const ushort* __restrict__ x16,
                                                       const ushort* __restrict__ Uh16,
                                                       const ushort* __restrict__ Ul16,
                                                       unsigned char* __restrict__ UkT8)
{
  int bidx = blockIdx.x;
  int b   = bidx >> 3;
  int sub = bidx & 7;
  int vs  = sub >> 2;
  int wsb = sub & 3;
  int tid = threadIdx.x;
  int wave = tid >> 6;
  int lane = tid & 63;
  int lr = lane & 15;
  int lk = lane >> 4;

  int v_base = vs * 64 + wave * 16;
  int w_blk  = wsb * 128;

  bf16x8 ah[4], al[4];
#pragma unroll
  for (int kt = 0; kt < 4; ++kt) {
    ah[kt] = *(const bf16x8*)(Uh16 + (size_t)(v_base + lr) * 128 + kt * 32 + lk * 8);
    al[kt] = *(const bf16x8*)(Ul16 + (size_t)(v_base + lr) * 128 + kt * 32 + lk * 8);
  }

#pragma unroll
  for (int wt = 0; wt < 8; ++wt) {
    int w0 = w_blk + wt * 16;
    bf16x8 bv[4];
#pragma unroll
    for (int kt = 0; kt < 4; ++kt)
      bv[kt] = *(const bf16x8*)(x16 + ((size_t)b * 512 + w0 + lr) * 128 + kt * 32 + lk * 8);
    f32x4 acch = {0.f, 0.f, 0.f, 0.f};
    f32x4 accl = {0.f, 0.f, 0.f, 0.f};
#pragma unroll
    for (int kt = 0; kt < 4; ++kt) {
      acch = __builtin_amdgcn_mfma_f32_16x16x32_bf16(ah[kt], bv[kt], acch, 0, 0, 0);
      accl = __builtin_amdgcn_mfma_f32_16x16x32_bf16(al[kt], bv[kt], accl, 0, 0, 0);
    }
    f32x4 acc = acch + accl;
    uint32_t q = q8(acc[0], 16.f) | (q8(acc[1], 16.f) << 8) |
                 (q8(acc[2], 16.f) << 16) | (q8(acc[3], 16.f) << 24);
    *(uint32_t*)(UkT8 + ((size_t)b * 512 + w0 + lr) * 128 + v_base + lk * 4) = q;
  }
}

// ---------------- per-step K1: lstm(t-1) + [tqs; y] = A32 @ [s;c] ----------------
__global__ __launch_bounds__(512) void lstm_qy(const float* __restrict__ g0,
    const float* __restrict__ g1, const float* __restrict__ c_in,
    float* __restrict__ c_out, float* __restrict__ s, float* __restrict__ ybuf,
    const float* __restrict__ A32, const float* __restrict__ bd,
    float* __restrict__ tqs_g, float* __restrict__ outy, int t)
{
  __shared__ float q_lds[8][512];
  int tid = threadIdx.x;
  int b0 = blockIdx.x * 8;
  int strip = blockIdx.y;

  if (t > 0) {
#pragma unroll
    for (int rep = 0; rep < 4; ++rep) {
      int cell = tid + rep * 512;
      int bl = cell >> 8, h = cell & 255;
      int b = b0 + bl;
      size_t gb = (size_t)b * 1024;
      float gi = g0[gb + h]       + g1[gb + h];
      float gf = g0[gb + 256 + h] + g1[gb + 256 + h];
      float gg = g0[gb + 512 + h] + g1[gb + 512 + h];
      float go = g0[gb + 768 + h] + g1[gb + 768 + h];
      float cv = c_in[b * 256 + h];
      float cn = sigmoid_fast(gf) * cv + sigmoid_fast(gi) * tanh_fast(gg);
      float sn = sigmoid_fast(go) * tanh_fast(cn);
      q_lds[bl][h] = sn;
      q_lds[bl][256 + h] = cn;
      if (strip == 0) { c_out[b * 256 + h] = cn; s[b * 256 + h] = sn; }
    }
  } else {
#pragma unroll
    for (int rep = 0; rep < 4; ++rep) {
      int cell = tid + rep * 512;
      int bl = cell >> 8, h = cell & 255;
      q_lds[bl][h] = 0.f; q_lds[bl][256 + h] = 0.f;
    }
  }
  __syncthreads();

  int r = strip * 64 + (tid & 63);
  int tb = tid >> 6;
  int b = b0 + tb;
  float acc0 = (r < 128) ? -8.0f : bd[r - 128];
  float acc1 = 0.f, acc2 = 0.f, acc3 = 0.f;
  const float* ap = A32 + r;
  const float* qp = &q_lds[tb][0];
#pragma unroll 8
  for (int k = 0; k < 512; k += 4) {
    float4 q4 = *(const float4*)(qp + k);           // ds_read_b128, wave-broadcast
    acc0 = fmaf(ap[(size_t)(k + 0) * 192], q4.x, acc0);
    acc1 = fmaf(ap[(size_t)(k + 1) * 192], q4.y, acc1);
    acc2 = fmaf(ap[(size_t)(k + 2) * 192], q4.z, acc2);
    acc3 = fmaf(ap[(size_t)(k + 3) * 192], q4.w, acc3);
  }
  float acc = (acc0 + acc1) + (acc2 + acc3);
  if (r < 128) {
    tqs_g[b * 128 + r] = acc;                         // = 2log2e*wq - 8
  } else if (t > 0) {
    int d = r - 128;
    ybuf[b * 64 + d] = acc;
    outy[(size_t)b * PLENN * 64 + (size_t)(t - 1) * 64 + d] = acc;
  }
}

// ---------------- per-step K2: e-pass + softmax + ctx ----------------
__global__ __launch_bounds__(512, 4) void attn_stream(const unsigned char* __restrict__ UkT8,
    const unsigned char* __restrict__ x8q, const float* __restrict__ tqs_g,
    const float* __restrict__ m2vv_g, float* __restrict__ ctx,
    float* __restrict__ wout, int t)
{
  __shared__ float tqs[128];
  __shared__ float m2vv[128];
  __shared__ float e_sh[512];
  __shared__ float watt[512];
  __shared__ float red[16];
  __shared__ float scratch[1088];   // 8 waves x 136
  int tid = threadIdx.x;
  int b = blockIdx.x;

  if (tid < 128) tqs[tid] = tqs_g[b * 128 + tid];
  else if (tid < 256) m2vv[tid - 128] = m2vv_g[tid - 128];
  __syncthreads();

  // ---- phase C: e-pass; thread (vs=tid&7 -> 16 v in one uint4, wg=tid>>3 -> 8 w @64) ----
  {
    int vs = tid & 7, wg = tid >> 3;
    float tq[16], mv[16];
#pragma unroll
    for (int q4 = 0; q4 < 4; ++q4) {
      float4 t4 = *(const float4*)&tqs[vs * 16 + q4 * 4];
      float4 m4 = *(const float4*)&m2vv[vs * 16 + q4 * 4];
      tq[q4 * 4 + 0] = t4.x; tq[q4 * 4 + 1] = t4.y; tq[q4 * 4 + 2] = t4.z; tq[q4 * 4 + 3] = t4.w;
      mv[q4 * 4 + 0] = m4.x; mv[q4 * 4 + 1] = m4.y; mv[q4 * 4 + 2] = m4.z; mv[q4 * 4 + 3] = m4.w;
    }
    float a8[8];
#pragma unroll
    for (int wi = 0; wi < 8; ++wi) {
      int w = wg + wi * 64;
      uint4 r0 = *(const uint4*)(UkT8 + ((size_t)b * 512 + w) * 128 + vs * 16);
      float a = 0.f;
      a = sterm(r0.x, 0, tq[ 0], mv[ 0], a);
      a = sterm(r0.x, 1, tq[ 1], mv[ 1], a);
      a = sterm(r0.x, 2, tq[ 2], mv[ 2], a);
      a = sterm(r0.x, 3, tq[ 3], mv[ 3], a);
      a = sterm(r0.y, 0, tq[ 4], mv[ 4], a);
      a = sterm(r0.y, 1, tq[ 5], mv[ 5], a);
      a = sterm(r0.y, 2, tq[ 6], mv[ 6], a);
      a = sterm(r0.y, 3, tq[ 7], mv[ 7], a);
      a = sterm(r0.z, 0, tq[ 8], mv[ 8], a);
      a = sterm(r0.z, 1, tq[ 9], mv[ 9], a);
      a = sterm(r0.z, 2, tq[10], mv[10], a);
      a = sterm(r0.z, 3, tq[11], mv[11], a);
      a = sterm(r0.w, 0, tq[12], mv[12], a);
      a = sterm(r0.w, 1, tq[13], mv[13], a);
      a = sterm(r0.w, 2, tq[14], mv[14], a);
      a = sterm(r0.w, 3, tq[15], mv[15], a);
      a8[wi] = a;
    }
#pragma unroll
    for (int wi = 0; wi < 8; ++wi) {
      a8[wi] += __shfl_xor(a8[wi], 1);
      a8[wi] += __shfl_xor(a8[wi], 2);
      a8[wi] += __shfl_xor(a8[wi], 4);
    }
    if (vs == 0) {
#pragma unroll
      for (int wi = 0; wi < 8; ++wi) e_sh[wg + wi * 64] = a8[wi];
    }
  }
  __syncthreads();

  // ---- softmax over 512 w ----
  float e = e_sh[tid];
  float m = e;
#pragma unroll
  for (int o = 32; o > 0; o >>= 1) m = fmaxf(m, __shfl_xor(m, o));
  if ((tid & 63) == 0) red[tid >> 6] = m;
  __syncthreads();
  float M = red[0];
#pragma unroll
  for (int i2 = 1; i2 < 8; ++i2) M = fmaxf(M, red[i2]);
  float p = __expf(e - M);
  float wsum = p;
#pragma unroll
  for (int o = 32; o > 0; o >>= 1) wsum += __shfl_xor(wsum, o);
  if ((tid & 63) == 0) red[8 + (tid >> 6)] = wsum;
  __syncthreads();
  float S = red[8] + red[9] + red[10] + red[11] + red[12] + red[13] + red[14] + red[15];
  float wv = p * __builtin_amdgcn_rcpf(S);
  watt[tid] = wv;
  wout[(size_t)b * PLENN * 512 + (size_t)t * 512 + tid] = wv;
  __syncthreads();

  // ---- phase E: ctx partials from uint8 x; shfl-reduce over the wave's 4 wch groups ----
  {
    int dg = tid & 15, wch = tid >> 4;
    int wv_id = tid >> 6, lane = tid & 63;
    float a8[8];
#pragma unroll
    for (int i = 0; i < 8; ++i) a8[i] = 0.f;
    const unsigned char* xp = x8q + ((size_t)(b * 512 + wch * 16)) * 128 + dg * 8;
#pragma unroll 4
    for (int wi = 0; wi < 16; ++wi) {
      uint2 raw = *(const uint2*)(xp + (size_t)wi * 128);
      float wgt = watt[wch * 16 + wi];
      a8[0] = fmaf(wgt, ub(raw.x, 0), a8[0]);
      a8[1] = fmaf(wgt, ub(raw.x, 1), a8[1]);
      a8[2] = fmaf(wgt, ub(raw.x, 2), a8[2]);
      a8[3] = fmaf(wgt, ub(raw.x, 3), a8[3]);
      a8[4] = fmaf(wgt, ub(raw.y, 0), a8[4]);
      a8[5] = fmaf(wgt, ub(raw.y, 1), a8[5]);
      a8[6] = fmaf(wgt, ub(raw.y, 2), a8[6]);
      a8[7] = fmaf(wgt, ub(raw.y, 3), a8[7]);
    }
#pragma unroll
    for (int i = 0; i < 8; ++i) {
      a8[i] += __shfl_xor(a8[i], 16);
      a8[i] += __shfl_xor(a8[i], 32);
    }
    if (lane < 16) {
      *(float4*)&scratch[wv_id * 136 + dg * 8]     = make_float4(a8[0], a8[1], a8[2], a8[3]);
      *(float4*)&scratch[wv_id * 136 + dg * 8 + 4] = make_float4(a8[4], a8[5], a8[6], a8[7]);
    }
  }
  __syncthreads();
  if (tid < 128) {
    float a = 0.f;
#pragma unroll
    for (int k = 0; k < 8; ++k) a += scratch[k * 136 + tid];
    ctx[b * 128 + tid] = fmaf(a, XS, -128.0f * XS);   // sum(w)==1
  }
}

// ---------------- per-step K3: gates GEMM (bf16 B), 32x64 tiles ----------------
__global__ __launch_bounds__(256) void gates_gemm(const float* __restrict__ y,
    const float* __restrict__ ctx, const float* __restrict__ s,
    const ushort* __restrict__ WihT16, const float* __restrict__ bias,
    float* __restrict__ g0, float* __restrict__ g1)
{
  __shared__ float As[32][36];
  __shared__ float Bs[32][68];
  int tid = threadIdx.x;
  int bm = blockIdx.x;
  int bn = blockIdx.y;
  int kz = blockIdx.z;
  int tr = tid & 15, tc = tid >> 4;
  float acc[2][4];
#pragma unroll
  for (int i = 0; i < 2; ++i)
#pragma unroll
    for (int j = 0; j < 4; ++j) acc[i][j] = 0.f;

  for (int kt = 0; kt < 7; ++kt) {
    int k0 = kz * 224 + kt * 32;
    const float* Ab; int stride, off;
    if (k0 < 64)       { Ab = y;   stride = 64;  off = 0; }
    else if (k0 < 192) { Ab = ctx; stride = 128; off = 64; }
    else               { Ab = s;   stride = 256; off = 192; }
#pragma unroll
    for (int i = 0; i < 4; ++i) {
      int idx = tid + i * 256;
      int r = idx >> 5, kk = idx & 31;
      As[kk][r] = Ab[(size_t)(bm * 32 + r) * stride + (k0 - off) + kk];
    }
#pragma unroll
    for (int i = 0; i < 4; ++i) {
      int idx = tid + i * 256;
      int kk = idx >> 5, cp = idx & 31;
      uint32_t w2 = *(const uint32_t*)(WihT16 + (size_t)(k0 + kk) * 1024 + bn * 64 + cp * 2);
      Bs[kk][cp * 2]     = bflo(w2);
      Bs[kk][cp * 2 + 1] = bfhi(w2);
    }
    __syncthreads();
#pragma unroll 8
    for (int kk = 0; kk < 32; ++kk) {
      float2 a2 = *(const float2*)&As[kk][tr * 2];
      float4 b4 = *(const float4*)&Bs[kk][tc * 4];
      acc[0][0] = fmaf(a2.x, b4.x, acc[0][0]);
      acc[0][1] = fmaf(a2.x, b4.y, acc[0][1]);
      acc[0][2] = fmaf(a2.x, b4.z, acc[0][2]);
      acc[0][3] = fmaf(a2.x, b4.w, acc[0][3]);
      acc[1][0] = fmaf(a2.y, b4.x, acc[1][0]);
      acc[1][1] = fmaf(a2.y, b4.y, acc[1][1]);
      acc[1][2] = fmaf(a2.y, b4.z, acc[1][2]);
      acc[1][3] = fmaf(a2.y, b4.w, acc[1][3]);
    }
    __syncthreads();
  }
  float* dst = kz ? g1 : g0;
#pragma unroll
  for (int i = 0; i < 2; ++i) {
    int bb = bm * 32 + tr * 2 + i;
    int g  = bn * 64 + tc * 4;
    float4 o4;
    o4.x = acc[i][0] + (kz == 0 ? bias[g + 0] : 0.f);
    o4.y = acc[i][1] + (kz == 0 ? bias[g + 1] : 0.f);
    o4.z = acc[i][2] + (kz == 0 ? bias[g + 2] : 0.f);
    o4.w = acc[i][3] + (kz == 0 ? bias[g + 3] : 0.f);
    *(float4*)(dst + (size_t)bb * 1024 + g) = o4;
  }
}

// ---------------- tail: final lstm + y ----------------
__global__ __launch_bounds__(256) void lstm_tail(const float* __restrict__ g0,
    const float* __restrict__ g1, const float* __restrict__ c_in,
    const float* __restrict__ Wdt, const float* __restrict__ bd,
    float* __restrict__ outy, int t)
{
  __shared__ float ssh[256];
  int b = blockIdx.x, h = threadIdx.x;
  size_t gb = (size_t)b * 1024;
  float gi = g0[gb + h]       + g1[gb + h];
  float gf = g0[gb + 256 + h] + g1[gb + 256 + h];
  float gg = g0[gb + 512 + h] + g1[gb + 512 + h];
  float go = g0[gb + 768 + h] + g1[gb + 768 + h];
  float cv = c_in[b * 256 + h];
  float cn = sigmoid_fast(gf) * cv + sigmoid_fast(gi) * tanh_fast(gg);
  float sn = sigmoid_fast(go) * tanh_fast(cn);
  ssh[h] = sn;
  __syncthreads();
  if (h < 64) {
    float a = bd[h];
#pragma unroll 4
    for (int k = 0; k < 256; ++k) a = fmaf(ssh[k], Wdt[k * 64 + h], a);
    outy[(size_t)b * PLENN * 64 + (size_t)t * 64 + h] = a;
  }
}

extern "C" void kernel_launch(void* const* d_in, const int* in_sizes, int n_in,
                              void* d_out, int out_size, void* d_ws, size_t ws_size,
                              hipStream_t stream)
{
  (void)in_sizes; (void)n_in; (void)out_size; (void)ws_size;
  const float* x    = (const float*)d_in[0];
  const float* V    = (const float*)d_in[2];
  const float* W    = (const float*)d_in[3];
  const float* U    = (const float*)d_in[4];
  const float* W_ih = (const float*)d_in[5];
  const float* W_hh = (const float*)d_in[6];
  const float* b_ih = (const float*)d_in[7];
  const float* b_hh = (const float*)d_in[8];
  const float* Wd   = (const float*)d_in[9];
  const float* bd   = (const float*)d_in[10];

  float* out  = (float*)d_out;
  float* outy = out;                                   // predict_y (B,64,64)
  float* outw = out + (size_t)BB * PLENN * DOUTN;      // weight    (B,64,512)

  float* ws = (float*)d_ws;
  size_t o = 0;
  unsigned char* UkT8 = (unsigned char*)(ws + o); o += (size_t)BB * DIN * WINN / 4;
  unsigned char* x8q  = (unsigned char*)(ws + o); o += (size_t)BB * WINN * DIN / 4;
  ushort* x16  = (ushort*)(ws + o); o += (size_t)BB * WINN * DIN / 2;
  float* A32  = ws + o; o += 512 * 192;
  ushort* WihT16 = (ushort*)(ws + o); o += 448 * 1024 / 2;
  float* Wdt  = ws + o; o += 256 * 64;
  float* bias = ws + o; o += 1024;
  float* m2vv = ws + o; o += 128;
  ushort* Uh16 = (ushort*)(ws + o); o += 128 * 128 / 2;
  ushort* Ul16 = (ushort*)(ws + o); o += 128 * 128 / 2;
  float* sbuf = ws + o; o += (size_t)BB * HIDN;
  float* cbuf = ws + o; o += (size_t)2 * BB * HIDN;    // ping-pong
  float* ybuf = ws + o; o += (size_t)BB * DOUTN;
  float* ctx  = ws + o; o += (size_t)BB * DIN;
  float* tqs_g = ws + o; o += (size_t)BB * DIN;
  float* g0   = ws + o; o += (size_t)BB * G4;
  float* g1   = ws + o; o += (size_t)BB * G4;

  hipMemsetAsync(sbuf, 0, (size_t)BB * HIDN * sizeof(float), stream);
  hipMemsetAsync(cbuf, 0, (size_t)2 * BB * HIDN * sizeof(float), stream);
  hipMemsetAsync(ybuf, 0, (size_t)BB * DOUTN * sizeof(float), stream);

  prep_weights<<<1792, 256, 0, stream>>>(W, W_ih, W_hh, b_ih, b_hh, Wd, V, U,
                                         A32, WihT16, Wdt, bias, m2vv, Uh16, Ul16);
  convert_x<<<16384, 256, 0, stream>>>(x, x16, x8q);
  compute_uk_mfma<<<4096, 256, 0, stream>>>(x16, Uh16, Ul16, UkT8);

  for (int t = 0; t < PLENN; ++t) {
    const float* cin = cbuf + (size_t)((t + 1) & 1) * BB * HIDN;
    float* cout      = cbuf + (size_t)(t & 1) * BB * HIDN;
    lstm_qy<<<dim3(64, 3), 512, 0, stream>>>(g0, g1, cin, cout, sbuf, ybuf,
                                             A32, bd, tqs_g, outy, t);
    attn_stream<<<BB, 512, 0, stream>>>(UkT8, x8q, tqs_g, m2vv, ctx, outw, t);
    gates_gemm<<<dim3(16, 16, 2), 256, 0, stream>>>(ybuf, ctx, sbuf, WihT16, bias, g0, g1);
  }
  lstm_tail<<<BB, 256, 0, stream>>>(g0, g1, cbuf + (size_t)BB * HIDN,
                                    Wdt, bd, outy, PLENN - 1);
}